// Round 23
// baseline (117.508 us; speedup 1.0000x reference)
//
#include <hip/hip_runtime.h>
#include <hip/hip_bf16.h>

typedef __attribute__((ext_vector_type(8))) short bf16x8;
typedef __attribute__((ext_vector_type(4))) float f32x4;
typedef __attribute__((ext_vector_type(4))) short sh4;

static constexpr int NTOK = 8192;   // B*T
static constexpr int D = 1024;
static constexpr int E = 8;
static constexpr int H = 1024;
static constexpr int BM = 128;      // tokens per tile
static constexpr int BK = 64;       // K-step
static constexpr int NWAVE = NTOK / 64;  // 128
static constexpr int MSLOT = 16;         // m-tiles per expert covered (<=2048 tokens)
static constexpr int TBLK = 6144;        // transpose blocks: 24 matrices x 256 tiles

__device__ __forceinline__ unsigned short f2bf(float f) {
  unsigned u = __builtin_bit_cast(unsigned, f);
  u = (u + 0x7FFFu + ((u >> 16) & 1u)) >> 16;   // round-to-nearest-even
  return (unsigned short)u;
}

__device__ __forceinline__ void gload16(const void* g, void* l) {
  __builtin_amdgcn_global_load_lds(
      (const __attribute__((address_space(1))) unsigned int*)g,
      (__attribute__((address_space(3))) unsigned int*)l, 16, 0, 0);
}

// per-thread prefix over counts (predicated, no dynamic indexing)
__device__ __forceinline__ void expert_span(const int* __restrict__ counts,
                                            int e, int& off, int& cnt) {
  off = 0; cnt = 0;
#pragma unroll
  for (int i = 0; i < E; ++i) {
    int ci = counts[i];
    off += (i < e) ? ci : 0;
    cnt = (i == e) ? ci : cnt;
  }
}

// ------------- fused prep: bank transpose (blocks 0..6143) + router (6144..8191) -------------
// Transpose reads use non-temporal loads (read-once 96 MB stream -> don't thrash L2).
__global__ __launch_bounds__(256) void k_prep(
    const float* __restrict__ x, const float* __restrict__ Wg,
    const float* __restrict__ gate, const float* __restrict__ up,
    const float* __restrict__ down, unsigned short* __restrict__ xb,
    int* __restrict__ sel, unsigned short* __restrict__ gt,
    unsigned short* __restrict__ ut, unsigned short* __restrict__ dt) {
  __shared__ char smem[32768];
  int bid = blockIdx.x;
  int tid = threadIdx.x;
  if (bid < TBLK) {
    // ---- transpose: fp32 [k][n] -> bf16 [n][k], 64x64 tiles ----
    unsigned short (*T)[66] = (unsigned short(*)[66])smem;
    int m = bid >> 8;           // 0..23
    int rem2 = bid & 255;
    int mm = m & 7;
    const size_t MS = (size_t)1024 * 1024;
    const float* src;
    unsigned short* dst;
    if (m < 8)       { src = gate + mm * MS; dst = gt + mm * MS; }
    else if (m < 16) { src = up   + mm * MS; dst = ut + mm * MS; }
    else             { src = down + mm * MS; dst = dt + mm * MS; }
    int tk0 = (rem2 & 15) * 64, tn0 = (rem2 >> 4) * 64;
    int rr = tid >> 4;          // 0..15
    int c4 = (tid & 15) * 4;    // col within tile (elements)
#pragma unroll
    for (int pass = 0; pass < 4; ++pass) {
      int r = pass * 16 + rr;   // tile k-row
      f32x4 v = __builtin_nontemporal_load(
          (const f32x4*)(src + (size_t)(tk0 + r) * 1024 + tn0 + c4));
      sh4 o;
      o.x = (short)f2bf(v.x); o.y = (short)f2bf(v.y);
      o.z = (short)f2bf(v.z); o.w = (short)f2bf(v.w);
      *(sh4*)&T[r][c4] = o;
    }
    __syncthreads();
#pragma unroll
    for (int pass = 0; pass < 4; ++pass) {
      int n = pass * 16 + rr;   // output row (original col)
      sh4 w;
      w.x = (short)T[c4 + 0][n];
      w.y = (short)T[c4 + 1][n];
      w.z = (short)T[c4 + 2][n];
      w.w = (short)T[c4 + 3][n];
      *(sh4*)(dst + (size_t)(tn0 + n) * 1024 + tk0 + c4) = w;
    }
  } else {
    // ---- router + x->bf16 convert ----
    float* wgs = (float*)smem;   // 8192 floats = 32 KB
    const float4* wg4 = (const float4*)Wg;
    float4* ws4 = (float4*)wgs;
    for (int i = tid; i < E * D / 4; i += 256) ws4[i] = wg4[i];
    __syncthreads();
    int lane = tid & 63;
    int t = (bid - TBLK) * 4 + (tid >> 6);
    const float4* xr = (const float4*)(x + (size_t)t * D);
    unsigned short* xo = xb + (size_t)t * D;
    float acc[E];
#pragma unroll
    for (int e = 0; e < E; ++e) acc[e] = 0.f;
#pragma unroll
    for (int j = 0; j < 4; ++j) {
      int idx = j * 64 + lane;
      float4 v = xr[idx];
      sh4 o;
      o.x = (short)f2bf(v.x); o.y = (short)f2bf(v.y);
      o.z = (short)f2bf(v.z); o.w = (short)f2bf(v.w);
      *(sh4*)(xo + idx * 4) = o;
#pragma unroll
      for (int e = 0; e < E; ++e) {
        float4 wv = *(const float4*)&wgs[e * D + idx * 4];
        acc[e] += v.x * wv.x + v.y * wv.y + v.z * wv.z + v.w * wv.w;
      }
    }
#pragma unroll
    for (int e = 0; e < E; ++e) {
#pragma unroll
      for (int off = 32; off; off >>= 1) acc[e] += __shfl_xor(acc[e], off, 64);
    }
    if (lane == 0) {
      int best = 0; float bv = acc[0];
#pragma unroll
      for (int e = 1; e < E; ++e) if (acc[e] > bv) { bv = acc[e]; best = e; }
      sel[t] = best;
    }
  }
}

// ---------------- per-wave histogram via ballot ----------------
__global__ __launch_bounds__(256) void k_wavecnt(
    const int* __restrict__ sel, int* __restrict__ wcnt) {
  int t = blockIdx.x * 256 + threadIdx.x;
  int lane = threadIdx.x & 63;
  int gwave = t >> 6;
  int s = sel[t];
#pragma unroll
  for (int e = 0; e < E; ++e) {
    unsigned long long m = __ballot(s == e);
    if (lane == 0) wcnt[e * NWAVE + gwave] = __popcll(m);
  }
}

// ------- scatter token list; per-block redundant scan over wcnt (replaces k_scan) -------
__global__ __launch_bounds__(256) void k_scatter(
    const int* __restrict__ sel, const int* __restrict__ wcnt,
    int* __restrict__ tlist, int* __restrict__ counts) {
  __shared__ int cnt[E][NWAVE];
  __shared__ int pre[E][NWAVE];
  __shared__ int eoff[E];
  int tid = threadIdx.x;
  if (tid < NWAVE) {
#pragma unroll
    for (int e = 0; e < E; ++e) cnt[e][tid] = wcnt[e * NWAVE + tid];
  }
  __syncthreads();
  if (tid < E) {
    int s = 0;
    for (int w = 0; w < NWAVE; ++w) { pre[tid][w] = s; s += cnt[tid][w]; }
    cnt[tid][0] = s;   // expert total (pre[] already captured)
  }
  __syncthreads();
  if (tid == 0) {
    int s = 0;
#pragma unroll
    for (int e = 0; e < E; ++e) { eoff[e] = s; s += cnt[e][0]; }
  }
  if (blockIdx.x == 0 && tid < E) counts[tid] = cnt[tid][0];
  __syncthreads();
  int t = blockIdx.x * 256 + tid;
  int lane = tid & 63;
  int gwave = t >> 6;
  int s = sel[t];
  unsigned long long below = (lane == 63) ? 0x7FFFFFFFFFFFFFFFull
                                          : ((1ull << lane) - 1ull);
  int rank = 0, base = 0;
#pragma unroll
  for (int e = 0; e < E; ++e) {
    unsigned long long m = __ballot(s == e);
    int r = __popcll(m & below);
    int b = eoff[e] + pre[e][gwave];
    rank = (e == s) ? r : rank;
    base = (e == s) ? b : base;
  }
  tlist[base + rank] = t;
}

// ---------------- grouped GEMM1: h = silu(x@G) * (x@U), bf16 out ----------------
// BN1=64 weight rows (per matrix), BM=128 tokens, BK=64; 2-deep ping-pong,
// counted vmcnt(8), 16 K-steps; row-XOR slot swizzle (slot ^= row&7).
__global__ __launch_bounds__(256, 2) void k_ffn1(
    const unsigned short* __restrict__ xb, const unsigned short* __restrict__ gt,
    const unsigned short* __restrict__ ut, const int* __restrict__ tlist,
    const int* __restrict__ counts, unsigned short* __restrict__ hbuf) {
  int e = blockIdx.x;                 // linear%8 == blockIdx.x -> XCD = expert
  int mt = blockIdx.y >> 4;           // 16 n-tiles of 64
  int n0 = (blockIdx.y & 15) * 64;
  int off, cnt;
  expert_span(counts, e, off, cnt);
  int rem = cnt - mt * BM;
  if (rem <= 0) return;
  if (rem > BM) rem = BM;
  int tid = threadIdx.x;
  int lane = tid & 63;
  int wid = tid >> 6;
  int wm = wid >> 1, wn = wid & 1;    // wm: 32-weight-row half, wn: 64-token half

  // [buf][ wg(64x64) | wu(64x64) | tf(128x64) ] = 16384 el = 32 KB; 2 bufs = 64 KB
  __shared__ unsigned short lds[2][16384];

  const unsigned short* gtb = gt + (size_t)e * D * H;
  const unsigned short* utb = ut + (size_t)e * D * H;

  int srow8 = lane >> 3;       // 0..7 (row within 8-row instr group)
  int hs8 = ((lane & 7) ^ srow8) * 8;   // pre-swizzled global k-slot (elements)

  const unsigned short *gS[2], *uS[2], *tS[4];
#pragma unroll
  for (int q = 0; q < 2; ++q) {
    int row = wid * 16 + q * 8 + srow8;            // wg/wu region row 0..63
    gS[q] = gtb + (size_t)(n0 + row) * D + hs8;
    uS[q] = utb + (size_t)(n0 + row) * D + hs8;
  }
#pragma unroll
  for (int q = 0; q < 4; ++q) {
    int row = wid * 32 + q * 8 + srow8;            // tf region row 0..127
    int tr = mt * BM + row; if (tr >= cnt) tr = cnt - 1;
    int tok = tlist[off + tr];
    tS[q] = xb + (size_t)tok * D + hs8;
  }

  auto STAGE = [&](int buf, int k0) {
    unsigned short* b = &lds[buf][0];
#pragma unroll
    for (int q = 0; q < 2; ++q) {
      gload16(gS[q] + k0, b + wid * 1024 + q * 512);
      gload16(uS[q] + k0, b + 4096 + wid * 1024 + q * 512);
    }
#pragma unroll
    for (int q = 0; q < 4; ++q)
      gload16(tS[q] + k0, b + 8192 + wid * 2048 + q * 512);
  };

  f32x4 accg[2][4], accu[2][4];
#pragma unroll
  for (int i = 0; i < 2; ++i)
#pragma unroll
    for (int j = 0; j < 4; ++j) { accg[i][j] = (f32x4)(0.f); accu[i][j] = (f32x4)(0.f); }

  int fr = lane & 15, s = lane >> 4;
  int x8 = fr & 7;
  int so0 = ((s ^ x8) & 7) * 8;          // ks=0 swizzled slot offset (elements)
  int so1 = (((4 + s) ^ x8) & 7) * 8;    // ks=1

  constexpr int NS = D / BK;  // 16
  STAGE(0, 0);
  for (int t = 0; t < NS; ++t) {
    int tn = t + 1; if (tn >= NS) tn = NS - 1;
    STAGE((t + 1) & 1, tn * BK);
    asm volatile("s_waitcnt vmcnt(8)" ::: "memory");
    __builtin_amdgcn_s_barrier();
    const unsigned short* L = lds[t & 1];
#pragma unroll
    for (int ks = 0; ks < 2; ++ks) {
      int so = ks ? so1 : so0;
      bf16x8 wg[2], wu[2], tf[4];
#pragma unroll
      for (int i = 0; i < 2; ++i) {
        int R = wm * 32 + i * 16 + fr;
        wg[i] = *(const bf16x8*)(L + R * 64 + so);
        wu[i] = *(const bf16x8*)(L + 4096 + R * 64 + so);
      }
#pragma unroll
      for (int j = 0; j < 4; ++j) {
        int R = wn * 64 + j * 16 + fr;
        tf[j] = *(const bf16x8*)(L + 8192 + R * 64 + so);
      }
#pragma unroll
      for (int i = 0; i < 2; ++i)
#pragma unroll
        for (int j = 0; j < 4; ++j) {
          accg[i][j] = __builtin_amdgcn_mfma_f32_16x16x32_bf16(wg[i], tf[j], accg[i][j], 0, 0, 0);
          accu[i][j] = __builtin_amdgcn_mfma_f32_16x16x32_bf16(wu[i], tf[j], accu[i][j], 0, 0, 0);
        }
    }
    __builtin_amdgcn_s_barrier();
  }
  asm volatile("s_waitcnt vmcnt(0)" ::: "memory");

  // epilogue: lane holds 4 consecutive output cols at one token -> sh4 stores
  int gr_base = off + mt * BM;
#pragma unroll
  for (int j = 0; j < 4; ++j) {
    int tl = wn * 64 + j * 16 + fr;
    if (tl < rem) {
      size_t tb = (size_t)(gr_base + tl) * H + n0 + wm * 32 + s * 4;
#pragma unroll
      for (int i = 0; i < 2; ++i) {
        sh4 v;
#pragma unroll
        for (int q = 0; q < 4; ++q) {
          float a = accg[i][j][q];
          float u = accu[i][j][q];
          float hv = (a / (1.f + __expf(-a))) * u;
          ((short*)&v)[q] = (short)f2bf(hv);
        }
        *(sh4*)(hbuf + tb + i * 16) = v;
      }
    }
  }
}

// ---------------- grouped GEMM2: y = h @ Dt, scatter fp32 ----------------
// BN=128, BK=64; 2-deep ping-pong, vmcnt(8), 16 steps; float4 epilogue.
__global__ __launch_bounds__(256, 2) void k_ffn2(
    const unsigned short* __restrict__ hbuf, const unsigned short* __restrict__ dt,
    const int* __restrict__ tlist, const int* __restrict__ counts,
    float* __restrict__ y) {
  int e = blockIdx.x;
  int mt = blockIdx.y >> 3;
  int n0 = (blockIdx.y & 7) * 128;
  int off, cnt;
  expert_span(counts, e, off, cnt);
  int rem = cnt - mt * BM;
  if (rem <= 0) return;
  if (rem > BM) rem = BM;
  int tid = threadIdx.x;
  int lane = tid & 63;
  int wid = tid >> 6;
  int wm = wid >> 1, wn = wid & 1;

  // [buf][ wd(128x64) | tf(128x64) ] = 16384 el = 32 KB; 2 bufs = 64 KB
  __shared__ unsigned short lds[2][16384];

  const unsigned short* dtb = dt + (size_t)e * D * H;
  int gr0 = off + mt * BM;

  int srow8 = lane >> 3;
  int hs8 = ((lane & 7) ^ srow8) * 8;

  const unsigned short *dS[4], *tS[4];
#pragma unroll
  for (int q = 0; q < 4; ++q) {
    int row = wid * 32 + q * 8 + srow8;   // 0..127
    dS[q] = dtb + (size_t)(n0 + row) * H + hs8;
    tS[q] = hbuf + (size_t)(gr0 + row) * H + hs8;   // slack rows allocated
  }

  auto STAGE = [&](int buf, int k0) {
    unsigned short* b = &lds[buf][0];
#pragma unroll
    for (int q = 0; q < 4; ++q) {
      gload16(dS[q] + k0, b + wid * 2048 + q * 512);
      gload16(tS[q] + k0, b + 8192 + wid * 2048 + q * 512);
    }
  };

  f32x4 acc[4][4];
#pragma unroll
  for (int i = 0; i < 4; ++i)
#pragma unroll
    for (int j = 0; j < 4; ++j) acc[i][j] = (f32x4)(0.f);

  int fr = lane & 15, s = lane >> 4;
  int x8 = fr & 7;
  int so0 = ((s ^ x8) & 7) * 8;
  int so1 = (((4 + s) ^ x8) & 7) * 8;

  constexpr int NS = H / BK;  // 16
  STAGE(0, 0);
  for (int t = 0; t < NS; ++t) {
    int tn = t + 1; if (tn >= NS) tn = NS - 1;
    STAGE((t + 1) & 1, tn * BK);
    asm volatile("s_waitcnt vmcnt(8)" ::: "memory");
    __builtin_amdgcn_s_barrier();
    const unsigned short* L = lds[t & 1];
#pragma unroll
    for (int ks = 0; ks < 2; ++ks) {
      int so = ks ? so1 : so0;
      bf16x8 wd[4], tf[4];
#pragma unroll
      for (int i = 0; i < 4; ++i) {
        int R = wm * 64 + i * 16 + fr;
        wd[i] = *(const bf16x8*)(L + R * 64 + so);
      }
#pragma unroll
      for (int j = 0; j < 4; ++j) {
        int R = wn * 64 + j * 16 + fr;
        tf[j] = *(const bf16x8*)(L + 8192 + R * 64 + so);
      }
#pragma unroll
      for (int i = 0; i < 4; ++i)
#pragma unroll
        for (int j = 0; j < 4; ++j)
          acc[i][j] = __builtin_amdgcn_mfma_f32_16x16x32_bf16(wd[i], tf[j], acc[i][j], 0, 0, 0);
    }
    __builtin_amdgcn_s_barrier();
  }
  asm volatile("s_waitcnt vmcnt(0)" ::: "memory");

  // epilogue: float4 per frag at one token row
#pragma unroll
  for (int j = 0; j < 4; ++j) {
    int tl = wn * 64 + j * 16 + fr;
    if (tl < rem) {
      int tok = tlist[off + mt * BM + tl];
      size_t tb = (size_t)tok * D + n0 + wm * 64 + s * 4;
#pragma unroll
      for (int i = 0; i < 4; ++i) {
        float4 v;
        v.x = acc[i][j][0]; v.y = acc[i][j][1];
        v.z = acc[i][j][2]; v.w = acc[i][j][3];
        *(float4*)(y + tb + i * 16) = v;
      }
    }
  }
}

extern "C" void kernel_launch(void* const* d_in, const int* in_sizes, int n_in,
                              void* d_out, int out_size, void* d_ws, size_t ws_size,
                              hipStream_t stream) {
  const float* x = (const float*)d_in[0];
  const float* Wg = (const float*)d_in[1];
  const float* gate = (const float*)d_in[2];
  const float* up = (const float*)d_in[3];
  const float* down = (const float*)d_in[4];
  float* y = (float*)d_out;

  char* ws = (char*)d_ws;
  int* counts = (int*)ws;                    // 8 ints
  int* sel = (int*)(ws + 1024);              // 8192 ints
  int* wcnt = (int*)(ws + 40960);            // E*NWAVE ints
  int* tlist = (int*)(ws + 49152);           // 8192 ints
  size_t o = 131072;
  unsigned short* xb = (unsigned short*)(ws + o);  o += (size_t)NTOK * D * 2;
  unsigned short* gt = (unsigned short*)(ws + o);  o += (size_t)E * D * H * 2;
  unsigned short* ut = (unsigned short*)(ws + o);  o += (size_t)E * D * H * 2;
  unsigned short* dt = (unsigned short*)(ws + o);  o += (size_t)E * D * H * 2;
  unsigned short* hbuf = (unsigned short*)(ws + o);  // (NTOK+BM)*H bf16

  k_prep<<<TBLK + NTOK / 4, 256, 0, stream>>>(x, Wg, gate, up, down, xb, sel, gt, ut, dt);
  k_wavecnt<<<NTOK / 256, 256, 0, stream>>>(sel, wcnt);
  k_scatter<<<NTOK / 256, 256, 0, stream>>>(sel, wcnt, tlist, counts);
  dim3 g1(E, MSLOT * 16);  // x = expert (-> XCD), y = mt * 16 + n-tile
  k_ffn1<<<g1, 256, 0, stream>>>(xb, gt, ut, tlist, counts, hbuf);
  dim3 g2(E, MSLOT * 8);   // x = expert, y = mt * 8 + n-tile
  k_ffn2<<<g2, 256, 0, stream>>>(hbuf, dt, tlist, counts, y);
}

// Round 24
// 115.947 us; speedup vs baseline: 1.0135x; 1.0135x over previous
//
#include <hip/hip_runtime.h>
#include <hip/hip_bf16.h>

typedef __attribute__((ext_vector_type(8))) short bf16x8;
typedef __attribute__((ext_vector_type(4))) float f32x4;
typedef __attribute__((ext_vector_type(4))) short sh4;

static constexpr int NTOK = 8192;   // B*T
static constexpr int D = 1024;
static constexpr int E = 8;
static constexpr int H = 1024;
static constexpr int BM = 128;      // tokens per tile
static constexpr int BK = 64;       // K-step
static constexpr int NWAVE = NTOK / 64;  // 128
static constexpr int MSLOT = 16;         // m-tiles per expert covered (<=2048 tokens)
static constexpr int TBLK = 6144;        // transpose blocks: 24 matrices x 256 tiles

__device__ __forceinline__ unsigned short f2bf(float f) {
  unsigned u = __builtin_bit_cast(unsigned, f);
  u = (u + 0x7FFFu + ((u >> 16) & 1u)) >> 16;   // round-to-nearest-even
  return (unsigned short)u;
}

__device__ __forceinline__ void gload16(const void* g, void* l) {
  __builtin_amdgcn_global_load_lds(
      (const __attribute__((address_space(1))) unsigned int*)g,
      (__attribute__((address_space(3))) unsigned int*)l, 16, 0, 0);
}

// per-thread prefix over counts (predicated, no dynamic indexing)
__device__ __forceinline__ void expert_span(const int* __restrict__ counts,
                                            int e, int& off, int& cnt) {
  off = 0; cnt = 0;
#pragma unroll
  for (int i = 0; i < E; ++i) {
    int ci = counts[i];
    off += (i < e) ? ci : 0;
    cnt = (i == e) ? ci : cnt;
  }
}

// ------------- fused prep: bank transpose (blocks 0..6143) + router (6144..8191) -------------
__global__ __launch_bounds__(256) void k_prep(
    const float* __restrict__ x, const float* __restrict__ Wg,
    const float* __restrict__ gate, const float* __restrict__ up,
    const float* __restrict__ down, unsigned short* __restrict__ xb,
    int* __restrict__ sel, unsigned short* __restrict__ gt,
    unsigned short* __restrict__ ut, unsigned short* __restrict__ dt) {
  __shared__ char smem[32768];
  int bid = blockIdx.x;
  int tid = threadIdx.x;
  if (bid < TBLK) {
    // ---- transpose: fp32 [k][n] -> bf16 [n][k], 64x64 tiles ----
    unsigned short (*T)[66] = (unsigned short(*)[66])smem;
    int m = bid >> 8;           // 0..23
    int rem2 = bid & 255;
    int mm = m & 7;
    const size_t MS = (size_t)1024 * 1024;
    const float* src;
    unsigned short* dst;
    if (m < 8)       { src = gate + mm * MS; dst = gt + mm * MS; }
    else if (m < 16) { src = up   + mm * MS; dst = ut + mm * MS; }
    else             { src = down + mm * MS; dst = dt + mm * MS; }
    int tk0 = (rem2 & 15) * 64, tn0 = (rem2 >> 4) * 64;
    int rr = tid >> 4;          // 0..15
    int c4 = (tid & 15) * 4;    // col within tile (elements)
#pragma unroll
    for (int pass = 0; pass < 4; ++pass) {
      int r = pass * 16 + rr;   // tile k-row
      float4 v = *(const float4*)(src + (size_t)(tk0 + r) * 1024 + tn0 + c4);
      sh4 o;
      o.x = (short)f2bf(v.x); o.y = (short)f2bf(v.y);
      o.z = (short)f2bf(v.z); o.w = (short)f2bf(v.w);
      *(sh4*)&T[r][c4] = o;
    }
    __syncthreads();
#pragma unroll
    for (int pass = 0; pass < 4; ++pass) {
      int n = pass * 16 + rr;   // output row (original col)
      sh4 w;
      w.x = (short)T[c4 + 0][n];
      w.y = (short)T[c4 + 1][n];
      w.z = (short)T[c4 + 2][n];
      w.w = (short)T[c4 + 3][n];
      *(sh4*)(dst + (size_t)(tn0 + n) * 1024 + tk0 + c4) = w;
    }
  } else {
    // ---- router + x->bf16 convert ----
    float* wgs = (float*)smem;   // 8192 floats = 32 KB
    const float4* wg4 = (const float4*)Wg;
    float4* ws4 = (float4*)wgs;
    for (int i = tid; i < E * D / 4; i += 256) ws4[i] = wg4[i];
    __syncthreads();
    int lane = tid & 63;
    int t = (bid - TBLK) * 4 + (tid >> 6);
    const float4* xr = (const float4*)(x + (size_t)t * D);
    unsigned short* xo = xb + (size_t)t * D;
    float acc[E];
#pragma unroll
    for (int e = 0; e < E; ++e) acc[e] = 0.f;
#pragma unroll
    for (int j = 0; j < 4; ++j) {
      int idx = j * 64 + lane;
      float4 v = xr[idx];
      sh4 o;
      o.x = (short)f2bf(v.x); o.y = (short)f2bf(v.y);
      o.z = (short)f2bf(v.z); o.w = (short)f2bf(v.w);
      *(sh4*)(xo + idx * 4) = o;
#pragma unroll
      for (int e = 0; e < E; ++e) {
        float4 wv = *(const float4*)&wgs[e * D + idx * 4];
        acc[e] += v.x * wv.x + v.y * wv.y + v.z * wv.z + v.w * wv.w;
      }
    }
#pragma unroll
    for (int e = 0; e < E; ++e) {
#pragma unroll
      for (int off = 32; off; off >>= 1) acc[e] += __shfl_xor(acc[e], off, 64);
    }
    if (lane == 0) {
      int best = 0; float bv = acc[0];
#pragma unroll
      for (int e = 1; e < E; ++e) if (acc[e] > bv) { bv = acc[e]; best = e; }
      sel[t] = best;
    }
  }
}

// ---------------- per-wave histogram via ballot ----------------
__global__ __launch_bounds__(256) void k_wavecnt(
    const int* __restrict__ sel, int* __restrict__ wcnt) {
  int t = blockIdx.x * 256 + threadIdx.x;
  int lane = threadIdx.x & 63;
  int gwave = t >> 6;
  int s = sel[t];
#pragma unroll
  for (int e = 0; e < E; ++e) {
    unsigned long long m = __ballot(s == e);
    if (lane == 0) wcnt[e * NWAVE + gwave] = __popcll(m);
  }
}

// ------- scatter token list; per-block redundant scan over wcnt (replaces k_scan) -------
__global__ __launch_bounds__(256) void k_scatter(
    const int* __restrict__ sel, const int* __restrict__ wcnt,
    int* __restrict__ tlist, int* __restrict__ counts) {
  __shared__ int cnt[E][NWAVE];
  __shared__ int pre[E][NWAVE];
  __shared__ int eoff[E];
  int tid = threadIdx.x;
  if (tid < NWAVE) {
#pragma unroll
    for (int e = 0; e < E; ++e) cnt[e][tid] = wcnt[e * NWAVE + tid];
  }
  __syncthreads();
  if (tid < E) {
    int s = 0;
    for (int w = 0; w < NWAVE; ++w) { pre[tid][w] = s; s += cnt[tid][w]; }
    cnt[tid][0] = s;   // expert total (pre[] already captured)
  }
  __syncthreads();
  if (tid == 0) {
    int s = 0;
#pragma unroll
    for (int e = 0; e < E; ++e) { eoff[e] = s; s += cnt[e][0]; }
  }
  if (blockIdx.x == 0 && tid < E) counts[tid] = cnt[tid][0];
  __syncthreads();
  int t = blockIdx.x * 256 + tid;
  int lane = tid & 63;
  int gwave = t >> 6;
  int s = sel[t];
  unsigned long long below = (lane == 63) ? 0x7FFFFFFFFFFFFFFFull
                                          : ((1ull << lane) - 1ull);
  int rank = 0, base = 0;
#pragma unroll
  for (int e = 0; e < E; ++e) {
    unsigned long long m = __ballot(s == e);
    int r = __popcll(m & below);
    int b = eoff[e] + pre[e][gwave];
    rank = (e == s) ? r : rank;
    base = (e == s) ? b : base;
  }
  tlist[base + rank] = t;
}

// ---------------- grouped GEMM1: h = silu(x@G) * (x@U), bf16 out ----------------
// BN1=64 weight rows (per matrix), BM=128 tokens, BK=64; 2-deep ping-pong,
// counted vmcnt(8), 16 K-steps; row-XOR slot swizzle (slot ^= row&7).
__global__ __launch_bounds__(256, 2) void k_ffn1(
    const unsigned short* __restrict__ xb, const unsigned short* __restrict__ gt,
    const unsigned short* __restrict__ ut, const int* __restrict__ tlist,
    const int* __restrict__ counts, unsigned short* __restrict__ hbuf) {
  int e = blockIdx.x;                 // linear%8 == blockIdx.x -> XCD = expert
  int mt = blockIdx.y >> 4;           // 16 n-tiles of 64
  int n0 = (blockIdx.y & 15) * 64;
  int off, cnt;
  expert_span(counts, e, off, cnt);
  int rem = cnt - mt * BM;
  if (rem <= 0) return;
  if (rem > BM) rem = BM;
  int tid = threadIdx.x;
  int lane = tid & 63;
  int wid = tid >> 6;
  int wm = wid >> 1, wn = wid & 1;    // wm: 32-weight-row half, wn: 64-token half

  // [buf][ wg(64x64) | wu(64x64) | tf(128x64) ] = 16384 el = 32 KB; 2 bufs = 64 KB
  __shared__ unsigned short lds[2][16384];

  const unsigned short* gtb = gt + (size_t)e * D * H;
  const unsigned short* utb = ut + (size_t)e * D * H;

  int srow8 = lane >> 3;       // 0..7 (row within 8-row instr group)
  int hs8 = ((lane & 7) ^ srow8) * 8;   // pre-swizzled global k-slot (elements)

  const unsigned short *gS[2], *uS[2], *tS[4];
#pragma unroll
  for (int q = 0; q < 2; ++q) {
    int row = wid * 16 + q * 8 + srow8;            // wg/wu region row 0..63
    gS[q] = gtb + (size_t)(n0 + row) * D + hs8;
    uS[q] = utb + (size_t)(n0 + row) * D + hs8;
  }
#pragma unroll
  for (int q = 0; q < 4; ++q) {
    int row = wid * 32 + q * 8 + srow8;            // tf region row 0..127
    int tr = mt * BM + row; if (tr >= cnt) tr = cnt - 1;
    int tok = tlist[off + tr];
    tS[q] = xb + (size_t)tok * D + hs8;
  }

  auto STAGE = [&](int buf, int k0) {
    unsigned short* b = &lds[buf][0];
#pragma unroll
    for (int q = 0; q < 2; ++q) {
      gload16(gS[q] + k0, b + wid * 1024 + q * 512);
      gload16(uS[q] + k0, b + 4096 + wid * 1024 + q * 512);
    }
#pragma unroll
    for (int q = 0; q < 4; ++q)
      gload16(tS[q] + k0, b + 8192 + wid * 2048 + q * 512);
  };

  f32x4 accg[2][4], accu[2][4];
#pragma unroll
  for (int i = 0; i < 2; ++i)
#pragma unroll
    for (int j = 0; j < 4; ++j) { accg[i][j] = (f32x4)(0.f); accu[i][j] = (f32x4)(0.f); }

  int fr = lane & 15, s = lane >> 4;
  int x8 = fr & 7;
  int so0 = ((s ^ x8) & 7) * 8;          // ks=0 swizzled slot offset (elements)
  int so1 = (((4 + s) ^ x8) & 7) * 8;    // ks=1

  constexpr int NS = D / BK;  // 16
  STAGE(0, 0);
  for (int t = 0; t < NS; ++t) {
    int tn = t + 1; if (tn >= NS) tn = NS - 1;
    STAGE((t + 1) & 1, tn * BK);
    asm volatile("s_waitcnt vmcnt(8)" ::: "memory");
    __builtin_amdgcn_s_barrier();
    const unsigned short* L = lds[t & 1];
#pragma unroll
    for (int ks = 0; ks < 2; ++ks) {
      int so = ks ? so1 : so0;
      bf16x8 wg[2], wu[2], tf[4];
#pragma unroll
      for (int i = 0; i < 2; ++i) {
        int R = wm * 32 + i * 16 + fr;
        wg[i] = *(const bf16x8*)(L + R * 64 + so);
        wu[i] = *(const bf16x8*)(L + 4096 + R * 64 + so);
      }
#pragma unroll
      for (int j = 0; j < 4; ++j) {
        int R = wn * 64 + j * 16 + fr;
        tf[j] = *(const bf16x8*)(L + 8192 + R * 64 + so);
      }
#pragma unroll
      for (int i = 0; i < 2; ++i)
#pragma unroll
        for (int j = 0; j < 4; ++j) {
          accg[i][j] = __builtin_amdgcn_mfma_f32_16x16x32_bf16(wg[i], tf[j], accg[i][j], 0, 0, 0);
          accu[i][j] = __builtin_amdgcn_mfma_f32_16x16x32_bf16(wu[i], tf[j], accu[i][j], 0, 0, 0);
        }
    }
    __builtin_amdgcn_s_barrier();
  }
  asm volatile("s_waitcnt vmcnt(0)" ::: "memory");

  // epilogue: lane holds 4 consecutive output cols at one token -> sh4 stores
  int gr_base = off + mt * BM;
#pragma unroll
  for (int j = 0; j < 4; ++j) {
    int tl = wn * 64 + j * 16 + fr;
    if (tl < rem) {
      size_t tb = (size_t)(gr_base + tl) * H + n0 + wm * 32 + s * 4;
#pragma unroll
      for (int i = 0; i < 2; ++i) {
        sh4 v;
#pragma unroll
        for (int q = 0; q < 4; ++q) {
          float a = accg[i][j][q];
          float u = accu[i][j][q];
          float hv = (a / (1.f + __expf(-a))) * u;
          ((short*)&v)[q] = (short)f2bf(hv);
        }
        *(sh4*)(hbuf + tb + i * 16) = v;
      }
    }
  }
}

// ---------------- grouped GEMM2: y = h @ Dt, scatter fp32 ----------------
// BN=128, BK=64; 2-deep ping-pong, vmcnt(8), 16 steps; float4 epilogue.
__global__ __launch_bounds__(256, 2) void k_ffn2(
    const unsigned short* __restrict__ hbuf, const unsigned short* __restrict__ dt,
    const int* __restrict__ tlist, const int* __restrict__ counts,
    float* __restrict__ y) {
  int e = blockIdx.x;
  int mt = blockIdx.y >> 3;
  int n0 = (blockIdx.y & 7) * 128;
  int off, cnt;
  expert_span(counts, e, off, cnt);
  int rem = cnt - mt * BM;
  if (rem <= 0) return;
  if (rem > BM) rem = BM;
  int tid = threadIdx.x;
  int lane = tid & 63;
  int wid = tid >> 6;
  int wm = wid >> 1, wn = wid & 1;

  // [buf][ wd(128x64) | tf(128x64) ] = 16384 el = 32 KB; 2 bufs = 64 KB
  __shared__ unsigned short lds[2][16384];

  const unsigned short* dtb = dt + (size_t)e * D * H;
  int gr0 = off + mt * BM;

  int srow8 = lane >> 3;
  int hs8 = ((lane & 7) ^ srow8) * 8;

  const unsigned short *dS[4], *tS[4];
#pragma unroll
  for (int q = 0; q < 4; ++q) {
    int row = wid * 32 + q * 8 + srow8;   // 0..127
    dS[q] = dtb + (size_t)(n0 + row) * H + hs8;
    tS[q] = hbuf + (size_t)(gr0 + row) * H + hs8;   // slack rows allocated
  }

  auto STAGE = [&](int buf, int k0) {
    unsigned short* b = &lds[buf][0];
#pragma unroll
    for (int q = 0; q < 4; ++q) {
      gload16(dS[q] + k0, b + wid * 2048 + q * 512);
      gload16(tS[q] + k0, b + 8192 + wid * 2048 + q * 512);
    }
  };

  f32x4 acc[4][4];
#pragma unroll
  for (int i = 0; i < 4; ++i)
#pragma unroll
    for (int j = 0; j < 4; ++j) acc[i][j] = (f32x4)(0.f);

  int fr = lane & 15, s = lane >> 4;
  int x8 = fr & 7;
  int so0 = ((s ^ x8) & 7) * 8;
  int so1 = (((4 + s) ^ x8) & 7) * 8;

  constexpr int NS = H / BK;  // 16
  STAGE(0, 0);
  for (int t = 0; t < NS; ++t) {
    int tn = t + 1; if (tn >= NS) tn = NS - 1;
    STAGE((t + 1) & 1, tn * BK);
    asm volatile("s_waitcnt vmcnt(8)" ::: "memory");
    __builtin_amdgcn_s_barrier();
    const unsigned short* L = lds[t & 1];
#pragma unroll
    for (int ks = 0; ks < 2; ++ks) {
      int so = ks ? so1 : so0;
      bf16x8 wd[4], tf[4];
#pragma unroll
      for (int i = 0; i < 4; ++i) {
        int R = wm * 64 + i * 16 + fr;
        wd[i] = *(const bf16x8*)(L + R * 64 + so);
      }
#pragma unroll
      for (int j = 0; j < 4; ++j) {
        int R = wn * 64 + j * 16 + fr;
        tf[j] = *(const bf16x8*)(L + 8192 + R * 64 + so);
      }
#pragma unroll
      for (int i = 0; i < 4; ++i)
#pragma unroll
        for (int j = 0; j < 4; ++j)
          acc[i][j] = __builtin_amdgcn_mfma_f32_16x16x32_bf16(wd[i], tf[j], acc[i][j], 0, 0, 0);
    }
    __builtin_amdgcn_s_barrier();
  }
  asm volatile("s_waitcnt vmcnt(0)" ::: "memory");

  // epilogue: float4 per frag at one token row
#pragma unroll
  for (int j = 0; j < 4; ++j) {
    int tl = wn * 64 + j * 16 + fr;
    if (tl < rem) {
      int tok = tlist[off + mt * BM + tl];
      size_t tb = (size_t)tok * D + n0 + wm * 64 + s * 4;
#pragma unroll
      for (int i = 0; i < 4; ++i) {
        float4 v;
        v.x = acc[i][j][0]; v.y = acc[i][j][1];
        v.z = acc[i][j][2]; v.w = acc[i][j][3];
        *(float4*)(y + tb + i * 16) = v;
      }
    }
  }
}

extern "C" void kernel_launch(void* const* d_in, const int* in_sizes, int n_in,
                              void* d_out, int out_size, void* d_ws, size_t ws_size,
                              hipStream_t stream) {
  const float* x = (const float*)d_in[0];
  const float* Wg = (const float*)d_in[1];
  const float* gate = (const float*)d_in[2];
  const float* up = (const float*)d_in[3];
  const float* down = (const float*)d_in[4];
  float* y = (float*)d_out;

  char* ws = (char*)d_ws;
  int* counts = (int*)ws;                    // 8 ints
  int* sel = (int*)(ws + 1024);              // 8192 ints
  int* wcnt = (int*)(ws + 40960);            // E*NWAVE ints
  int* tlist = (int*)(ws + 49152);           // 8192 ints
  size_t o = 131072;
  unsigned short* xb = (unsigned short*)(ws + o);  o += (size_t)NTOK * D * 2;
  unsigned short* gt = (unsigned short*)(ws + o);  o += (size_t)E * D * H * 2;
  unsigned short* ut = (unsigned short*)(ws + o);  o += (size_t)E * D * H * 2;
  unsigned short* dt = (unsigned short*)(ws + o);  o += (size_t)E * D * H * 2;
  unsigned short* hbuf = (unsigned short*)(ws + o);  // (NTOK+BM)*H bf16

  k_prep<<<TBLK + NTOK / 4, 256, 0, stream>>>(x, Wg, gate, up, down, xb, sel, gt, ut, dt);
  k_wavecnt<<<NTOK / 256, 256, 0, stream>>>(sel, wcnt);
  k_scatter<<<NTOK / 256, 256, 0, stream>>>(sel, wcnt, tlist, counts);
  dim3 g1(E, MSLOT * 16);  // x = expert (-> XCD), y = mt * 16 + n-tile
  k_ffn1<<<g1, 256, 0, stream>>>(xb, gt, ut, tlist, counts, hbuf);
  dim3 g2(E, MSLOT * 8);   // x = expert, y = mt * 8 + n-tile
  k_ffn2<<<g2, 256, 0, stream>>>(hbuf, dt, tlist, counts, y);
}